// Round 3
// baseline (568.832 us; speedup 1.0000x reference)
//
#include <hip/hip_runtime.h>
#include <math.h>

#define CIN  32
#define COUT 64
#define KVOL 27
#define EPSF 1e-5f

typedef __attribute__((ext_vector_type(8))) short          short8;
typedef __attribute__((ext_vector_type(8))) unsigned short u16x8;
typedef __attribute__((ext_vector_type(4))) float          float4v;

__device__ __forceinline__ float eluf(float x) { return x > 0.f ? x : expm1f(x); }

// f32 -> bf16 round-to-nearest-even
__device__ __forceinline__ unsigned short f2bf(float x) {
    unsigned u = __float_as_uint(x);
    unsigned r = (u + 0x7FFFu + ((u >> 16) & 1u)) >> 16;
    return (unsigned short)r;
}
__device__ __forceinline__ unsigned pk2bf(float lo, float hi) {
    return (unsigned)f2bf(lo) | ((unsigned)f2bf(hi) << 16);
}
__device__ __forceinline__ float bf2f(unsigned short h) {
    return __uint_as_float(((unsigned)h) << 16);
}

// ---------------------------------------------------------------------------
// prep: fused cvt_w (blocks 0..54) + bucket build (next nbB blocks) +
// nbr-map inversion (next nbL*KVOL blocks). All three are independent.
// ---------------------------------------------------------------------------
__global__ void prep_kernel(const float* __restrict__ W1, const float* __restrict__ W2,
                            const float* __restrict__ Wd,
                            unsigned short* __restrict__ Wt1, unsigned short* __restrict__ Wt2,
                            unsigned short* __restrict__ Wdt,
                            const int* __restrict__ pool_seg, int* __restrict__ cnt,
                            int* __restrict__ bucket, int N,
                            const int* __restrict__ conv_out, const int* __restrict__ conv_in,
                            int* __restrict__ nbrT, int L, int M, int nbB, int nbL)
{
    int b = blockIdx.x, t = threadIdx.x;
    if (b < 55) {
        if (b == 54) {
            for (int e = t; e < CIN * COUT; e += 256) {
                int i = e >> 6, c = e & 63;
                Wdt[c * CIN + i] = f2bf(Wd[e]);
            }
            return;
        }
        const float* W = (b < 27) ? W1 : W2;
        unsigned short* Wt = (b < 27) ? Wt1 : Wt2;
        int k = (b < 27) ? b : b - 27;
        const float* src = W + (size_t)k * (COUT * COUT);
        unsigned short* dst = Wt + (size_t)k * (COUT * COUT);
        for (int e = t; e < COUT * COUT; e += 256) {
            int i = e >> 6, c = e & 63;
            dst[c * COUT + i] = f2bf(src[e]);
        }
        return;
    }
    b -= 55;
    if (b < nbB) {  // bucket: pooling cell = 2x2x4 -> capacity 16
        int j = b * 256 + t;
        if (j < N) {
            int s = pool_seg[j];
            int pos = atomicAdd(&cnt[s], 1);
            bucket[(size_t)s * 16 + pos] = j;
        }
        return;
    }
    b -= nbB;  // nbr: invert (k, pairlist) into nbrT[k][M]
    int k = b / nbL, blk = b - k * nbL;
    int idx = blk * 256 + t;
    if (idx < L) {
        int e = k * L + idx;
        int j = conv_out[e];
        if (j < M) nbrT[(size_t)k * M + j] = conv_in[e];
    }
}

// ---------------------------------------------------------------------------
// Transposed streaming down-conv: t^T = Wd^T @ feats^T, zero LDS in hot loop.
// ---------------------------------------------------------------------------
__global__ __launch_bounds__(256) void gemm_t_kernel(
    const float* __restrict__ feats, const unsigned short* __restrict__ Wdt,
    int N, unsigned short* __restrict__ t_bf, float* __restrict__ red0)
{
    __shared__ float red_s[64];
    __shared__ float red_q[64];
    int t = threadIdx.x;
    if (t < 64) { red_s[t] = 0.f; red_q[t] = 0.f; }
    __syncthreads();

    int w = t >> 6, lane = t & 63, l15 = lane & 15, quad = lane >> 4;

    short8 aw[4];
    #pragma unroll
    for (int mt = 0; mt < 4; ++mt)
        aw[mt] = *(const short8*)(Wdt + (size_t)(16 * mt + l15) * CIN + quad * 8);

    float s1[16], sq[16];
    #pragma unroll
    for (int e = 0; e < 16; ++e) { s1[e] = 0.f; sq[e] = 0.f; }

    int numTiles = (N + 15) >> 4;
    int stride = gridDim.x * 4;
    int tile = blockIdx.x * 4 + w;

    float4 c0 = make_float4(0.f, 0.f, 0.f, 0.f), c1 = c0;
    {
        int pt = tile * 16 + l15;
        if (tile < numTiles && pt < N) {
            const float4* s = (const float4*)(feats + (size_t)pt * CIN + quad * 8);
            c0 = s[0]; c1 = s[1];
        }
    }

    while (tile < numTiles) {
        int nt = tile + stride;
        float4 n0 = make_float4(0.f, 0.f, 0.f, 0.f), n1 = n0;
        {
            int npt = nt * 16 + l15;
            if (nt < numTiles && npt < N) {
                const float4* s = (const float4*)(feats + (size_t)npt * CIN + quad * 8);
                n0 = s[0]; n1 = s[1];
            }
        }
        union { short8 v; unsigned u[4]; } b;
        b.u[0] = pk2bf(c0.x, c0.y);
        b.u[1] = pk2bf(c0.z, c0.w);
        b.u[2] = pk2bf(c1.x, c1.y);
        b.u[3] = pk2bf(c1.z, c1.w);

        float4v acc[4];
        #pragma unroll
        for (int mt = 0; mt < 4; ++mt)
            acc[mt] = __builtin_amdgcn_mfma_f32_16x16x32_bf16(
                aw[mt], b.v, (float4v){0.f, 0.f, 0.f, 0.f}, 0, 0, 0);

        int pt = tile * 16 + l15;
        if (pt < N) {
            #pragma unroll
            for (int mt = 0; mt < 4; ++mt) {
                uint2 o;
                o.x = pk2bf(acc[mt][0], acc[mt][1]);
                o.y = pk2bf(acc[mt][2], acc[mt][3]);
                *(uint2*)(t_bf + (size_t)pt * COUT + mt * 16 + quad * 4) = o;
            }
        }
        #pragma unroll
        for (int mt = 0; mt < 4; ++mt)
            #pragma unroll
            for (int e = 0; e < 4; ++e) {
                float v = acc[mt][e];
                s1[mt * 4 + e] += v; sq[mt * 4 + e] += v * v;
            }
        c0 = n0; c1 = n1;
        tile = nt;
    }

    #pragma unroll
    for (int m = 1; m <= 8; m <<= 1) {
        #pragma unroll
        for (int e = 0; e < 16; ++e) {
            s1[e] += __shfl_xor(s1[e], m);
            sq[e] += __shfl_xor(sq[e], m);
        }
    }
    if (l15 == 0) {
        #pragma unroll
        for (int e = 0; e < 16; ++e) {
            int ch = (e >> 2) * 16 + quad * 4 + (e & 3);
            atomicAdd(&red_s[ch], s1[e]);
            atomicAdd(&red_q[ch], sq[e]);
        }
    }
    __syncthreads();
    float* dst = red0 + (size_t)(blockIdx.x & 3) * 128;
    if (t < 64)       atomicAdd(&dst[t], red_s[t]);
    else if (t < 128) atomicAdd(&dst[t], red_q[t - 64]);
}

// ---------------------------------------------------------------------------
// Gather-only pool with inlined BN0 finalize (scale/shift in LDS).
// ---------------------------------------------------------------------------
__global__ __launch_bounds__(256) void pool_max_kernel(
    const unsigned short* __restrict__ t_bf,
    const int* __restrict__ cnt, const int* __restrict__ bucket,
    const float* __restrict__ red0, const float* __restrict__ g0,
    const float* __restrict__ b0,
    unsigned short* __restrict__ down_bf, int M, int N)
{
    __shared__ float sc_s[64], sh_s[64];
    int t = threadIdx.x;
    if (t < 64) {
        float s = 0.f, q2 = 0.f;
        #pragma unroll
        for (int i = 0; i < 4; ++i) { s += red0[i * 128 + t]; q2 += red0[i * 128 + 64 + t]; }
        float m = s / (float)N;
        float var = q2 / (float)N - m * m;
        float sc = g0[t] / sqrtf(var + EPSF);
        sc_s[t] = sc;
        sh_s[t] = b0[t] - m * sc;
    }
    __syncthreads();

    int id = blockIdx.x * 256 + t;
    int s = id >> 4, cg = id & 15;
    if (s >= M) return;
    int n = cnt[s];
    const int4* bk4 = (const int4*)(bucket + (size_t)s * 16);
    float4 mx = make_float4(-INFINITY, -INFINITY, -INFINITY, -INFINITY);
    float4 mn = make_float4( INFINITY,  INFINITY,  INFINITY,  INFINITY);
    #pragma unroll
    for (int ch = 0; ch < 4; ++ch) {
        if (ch * 4 >= n) break;
        int4 b4 = bk4[ch];
        #pragma unroll
        for (int e = 0; e < 4; ++e) {
            int p = ch * 4 + e;
            if (p < n) {
                int idx = (e == 0) ? b4.x : (e == 1) ? b4.y : (e == 2) ? b4.z : b4.w;
                ushort4 v = *(const ushort4*)(t_bf + (size_t)idx * COUT + cg * 4);
                float f0 = bf2f(v.x), f1 = bf2f(v.y), f2 = bf2f(v.z), f3 = bf2f(v.w);
                mx.x = fmaxf(mx.x, f0); mn.x = fminf(mn.x, f0);
                mx.y = fmaxf(mx.y, f1); mn.y = fminf(mn.y, f1);
                mx.z = fmaxf(mx.z, f2); mn.z = fminf(mn.z, f2);
                mx.w = fmaxf(mx.w, f3); mn.w = fminf(mn.w, f3);
            }
        }
    }
    int c0 = cg * 4;
    float scx = sc_s[c0], scy = sc_s[c0 + 1], scz = sc_s[c0 + 2], scw = sc_s[c0 + 3];
    float shx = sh_s[c0], shy = sh_s[c0 + 1], shz = sh_s[c0 + 2], shw = sh_s[c0 + 3];
    ushort4 o;
    o.x = f2bf(eluf(scx * (scx >= 0.f ? mx.x : mn.x) + shx));
    o.y = f2bf(eluf(scy * (scy >= 0.f ? mx.y : mn.y) + shy));
    o.z = f2bf(eluf(scz * (scz >= 0.f ? mx.z : mn.z) + shz));
    o.w = f2bf(eluf(scw * (scw >= 0.f ? mx.w : mn.w) + shw));
    *(ushort4*)(down_bf + (size_t)s * COUT + c0) = o;
}

// o1t = bf16( ELU(scale1*o1 + shift1) ) with inlined BN finalize from red.
__global__ __launch_bounds__(256) void bn_elu_cvt_kernel(
    const float* __restrict__ o1, const float* __restrict__ red,
    const float* __restrict__ g, const float* __restrict__ bb,
    unsigned short* __restrict__ o1t, int n4, int M)
{
    __shared__ float sc_s[64], sh_s[64];
    int t = threadIdx.x;
    if (t < 64) {
        float m = red[t] / (float)M;
        float var = red[64 + t] / (float)M - m * m;
        float sc = g[t] / sqrtf(var + EPSF);
        sc_s[t] = sc;
        sh_s[t] = bb[t] - m * sc;
    }
    __syncthreads();
    int i = blockIdx.x * 256 + t;
    if (i < n4) {
        float4 v = ((const float4*)o1)[i];
        int c0 = (i & 15) * 4;
        ushort4 o;
        o.x = f2bf(eluf(v.x * sc_s[c0]     + sh_s[c0]));
        o.y = f2bf(eluf(v.y * sc_s[c0 + 1] + sh_s[c0 + 1]));
        o.z = f2bf(eluf(v.z * sc_s[c0 + 2] + sh_s[c0 + 2]));
        o.w = f2bf(eluf(v.w * sc_s[c0 + 3] + sh_s[c0 + 3]));
        ((ushort4*)o1t)[i] = o;
    }
}

// out = elu( elu(scale2*raw + shift2) + down ), inlined BN finalize.
__global__ __launch_bounds__(256) void final_kernel(
    float* __restrict__ out, const unsigned short* __restrict__ down_bf,
    const float* __restrict__ red, const float* __restrict__ g,
    const float* __restrict__ bb, int n4, int M)
{
    __shared__ float sc_s[64], sh_s[64];
    int t = threadIdx.x;
    if (t < 64) {
        float m = red[t] / (float)M;
        float var = red[64 + t] / (float)M - m * m;
        float sc = g[t] / sqrtf(var + EPSF);
        sc_s[t] = sc;
        sh_s[t] = bb[t] - m * sc;
    }
    __syncthreads();
    int i = blockIdx.x * 256 + t;
    if (i < n4) {
        float4 v = ((const float4*)out)[i];
        ushort4 d = ((const ushort4*)down_bf)[i];
        int c0 = (i & 15) * 4;
        v.x = eluf(eluf(v.x * sc_s[c0]     + sh_s[c0])     + bf2f(d.x));
        v.y = eluf(eluf(v.y * sc_s[c0 + 1] + sh_s[c0 + 1]) + bf2f(d.y));
        v.z = eluf(eluf(v.z * sc_s[c0 + 2] + sh_s[c0 + 2]) + bf2f(d.z));
        v.w = eluf(eluf(v.w * sc_s[c0 + 3] + sh_s[c0 + 3]) + bf2f(d.w));
        ((float4*)out)[i] = v;
    }
}

// ---------------------------------------------------------------------------
// MFMA implicit-GEMM sparse conv. v4: depth-2 register prefetch.
// Gather for offset k+2 is issued at the TOP of iteration k and ds_written at
// the END of iteration k+1 -> ~2 full iterations of latency slack (covers an
// L2/L3 round trip), vs depth-1's MFMA-phase-only slack. Two rotating register
// sets; idx chain kept 2 ahead. 256x64 tile, 512 thr, 80KB LDS (2 blocks/CU),
// XOR swizzle (0 bank conflicts), XCD-chunked bijective block swizzle,
// fused BN-stats epilogue (scratch aliased into W_lds).
// ---------------------------------------------------------------------------
__global__ __launch_bounds__(512) void conv_mfma_kernel(
    const unsigned short* __restrict__ in, const unsigned short* __restrict__ Wt,
    const int* __restrict__ nbrT, int M,
    float* __restrict__ out, float* __restrict__ red)
{
    __shared__ __align__(16) unsigned short A_lds[2][256 * 64];  // 64 KB
    __shared__ __align__(16) unsigned short W_lds[2][64 * 64];   // 16 KB
    int t = threadIdx.x;

    // XCD-chunked bijective remap (m204)
    int nwg = gridDim.x;
    int q = nwg >> 3, r = nwg & 7;
    int xcd = blockIdx.x & 7, pos = blockIdx.x >> 3;
    int sb = (xcd < r ? xcd * (q + 1) : r * (q + 1) + (xcd - r) * q) + pos;
    int base = sb * 256;

    int w = t >> 6, lane = t & 63, l15 = lane & 15, quad = lane >> 4;

    float4v acc[2][4];
    #pragma unroll
    for (int s = 0; s < 2; ++s)
        #pragma unroll
        for (int n = 0; n < 4; ++n)
            acc[s][n] = (float4v){0.f, 0.f, 0.f, 0.f};

    int ar = t >> 1, ah = t & 1;   // A staging: row (0..255), 64B-half
    int gj = base + ar;
    bool gv = (gj < M);
    int arx = ar & 7;
    int wc = t >> 3, wq = t & 7;   // W staging: row (0..63), 16B-slot
    int wcx = wc & 7;

    // LDS write offsets (shorts)
    int awo0 = ar * 64 + (((ah * 4 + 0) ^ arx) * 8);
    int awo1 = ar * 64 + (((ah * 4 + 1) ^ arx) * 8);
    int awo2 = ar * 64 + (((ah * 4 + 2) ^ arx) * 8);
    int awo3 = ar * 64 + (((ah * 4 + 3) ^ arx) * 8);
    int wwo  = wc * 64 + ((wq ^ wcx) * 8);

    const u16x8 z8 = (u16x8){0, 0, 0, 0, 0, 0, 0, 0};

    // ---- prologue: idx 0..3; gather k=0 (stage now) and k=1 (hold in regs) --
    int i0 = gv ? nbrT[gj] : -1;
    int i1 = gv ? nbrT[(size_t)M + gj] : -1;
    int i2 = gv ? nbrT[(size_t)2 * M + gj] : -1;
    int i3 = gv ? nbrT[(size_t)3 * M + gj] : -1;

    u16x8 pa0 = z8, pa1 = z8, pa2 = z8, pa3 = z8;
    if (i0 >= 0) {
        const u16x8* s = (const u16x8*)(in + (size_t)i0 * COUT + 32 * ah);
        pa0 = s[0]; pa1 = s[1]; pa2 = s[2]; pa3 = s[3];
    }
    u16x8 pw = *(const u16x8*)(Wt + wc * COUT + wq * 8);

    u16x8 ca0 = z8, ca1 = z8, ca2 = z8, ca3 = z8;  // holds data for k+1
    if (i1 >= 0) {
        const u16x8* s = (const u16x8*)(in + (size_t)i1 * COUT + 32 * ah);
        ca0 = s[0]; ca1 = s[1]; ca2 = s[2]; ca3 = s[3];
    }
    u16x8 cw = *(const u16x8*)(Wt + (COUT * COUT) + wc * COUT + wq * 8);

    *(u16x8*)(A_lds[0] + awo0) = pa0;
    *(u16x8*)(A_lds[0] + awo1) = pa1;
    *(u16x8*)(A_lds[0] + awo2) = pa2;
    *(u16x8*)(A_lds[0] + awo3) = pa3;
    *(u16x8*)(W_lds[0] + wwo) = pw;
    __syncthreads();

    u16x8 na0 = z8, na1 = z8, na2 = z8, na3 = z8, nw = z8;  // receives k+2

    auto step = [&](int k,
                    u16x8& c0, u16x8& c1, u16x8& c2, u16x8& c3, u16x8& cwv,
                    u16x8& x0, u16x8& x1, u16x8& x2, u16x8& x3, u16x8& xw) {
        // issue gather for k+2 into x-set (lands in LDS at end of iter k+1)
        if (k + 2 < KVOL) {
            x0 = z8; x1 = z8; x2 = z8; x3 = z8;
            if (i2 >= 0) {
                const u16x8* s = (const u16x8*)(in + (size_t)i2 * COUT + 32 * ah);
                x0 = s[0]; x1 = s[1]; x2 = s[2]; x3 = s[3];
            }
            xw = *(const u16x8*)(Wt + (size_t)(k + 2) * (COUT * COUT) + wc * COUT + wq * 8);
        }
        i2 = i3;
        i3 = (k + 4 < KVOL && gv) ? nbrT[(size_t)(k + 4) * M + gj] : -1;

        // compute on buf[k&1]
        const unsigned short* Ab = A_lds[k & 1];
        const unsigned short* Wb = W_lds[k & 1];
        #pragma unroll
        for (int kk = 0; kk < 64; kk += 32) {
            int slb = quad + (kk >> 3);
            int r0 = 32 * w + l15;
            short8 a0 = *(const short8*)(Ab + r0 * 64 + ((slb ^ (r0 & 7)) * 8));
            int r1 = r0 + 16;
            short8 a1 = *(const short8*)(Ab + r1 * 64 + ((slb ^ (r1 & 7)) * 8));
            #pragma unroll
            for (int nn = 0; nn < 4; ++nn) {
                int rb = 16 * nn + l15;
                short8 bfr = *(const short8*)(Wb + rb * 64 + ((slb ^ (rb & 7)) * 8));
                acc[0][nn] = __builtin_amdgcn_mfma_f32_16x16x32_bf16(a0, bfr, acc[0][nn], 0, 0, 0);
                acc[1][nn] = __builtin_amdgcn_mfma_f32_16x16x32_bf16(a1, bfr, acc[1][nn], 0, 0, 0);
            }
        }

        // drain c-set (data for k+1, loaded one iteration ago) to back buffer
        if (k + 1 < KVOL) {
            unsigned short* An = A_lds[(k + 1) & 1];
            *(u16x8*)(An + awo0) = c0;
            *(u16x8*)(An + awo1) = c1;
            *(u16x8*)(An + awo2) = c2;
            *(u16x8*)(An + awo3) = c3;
            *(u16x8*)(W_lds[(k + 1) & 1] + wwo) = cwv;
        }
        __syncthreads();
    };

    for (int k = 0; k < KVOL; k += 2) {
        step(k,     ca0, ca1, ca2, ca3, cw, na0, na1, na2, na3, nw);
        if (k + 1 < KVOL)
            step(k + 1, na0, na1, na2, na3, nw, ca0, ca1, ca2, ca3, cw);
    }

    // stores (C/D layout: col=lane&15, row=quad*4+reg)
    #pragma unroll
    for (int s = 0; s < 2; ++s) {
        int row = base + 32 * w + 16 * s + quad * 4;
        #pragma unroll
        for (int n = 0; n < 4; ++n) {
            int c = 16 * n + l15;
            #pragma unroll
            for (int e = 0; e < 4; ++e)
                if (row + e < M) out[(size_t)(row + e) * COUT + c] = acc[s][n][e];
        }
    }

    // fused BN stats (rows >= M are exact zeros); scratch aliased into W_lds
    float* red_s = (float*)(W_lds[0]);
    float* red_q = red_s + 64;
    if (t < 128) red_s[t] = 0.f;
    __syncthreads();
    #pragma unroll
    for (int n = 0; n < 4; ++n) {
        float s1 = 0.f, sq = 0.f;
        #pragma unroll
        for (int s = 0; s < 2; ++s)
            #pragma unroll
            for (int e = 0; e < 4; ++e) { float v = acc[s][n][e]; s1 += v; sq += v * v; }
        s1 += __shfl_xor(s1, 16); sq += __shfl_xor(sq, 16);
        s1 += __shfl_xor(s1, 32); sq += __shfl_xor(sq, 32);
        if (quad == 0) {
            atomicAdd(&red_s[16 * n + l15], s1);
            atomicAdd(&red_q[16 * n + l15], sq);
        }
    }
    __syncthreads();
    if (t < 64)       atomicAdd(&red[t], red_s[t]);
    else if (t < 128) atomicAdd(&red[t], red_q[t - 64]);
}

extern "C" void kernel_launch(void* const* d_in, const int* in_sizes, int n_in,
                              void* d_out, int out_size, void* d_ws, size_t ws_size,
                              hipStream_t stream)
{
    (void)n_in; (void)ws_size;
    const float* feats    = (const float*)d_in[0];
    const float* Wd       = (const float*)d_in[1];
    const float* g0       = (const float*)d_in[2];
    const float* b0       = (const float*)d_in[3];
    const float* W1       = (const float*)d_in[4];
    const float* g1       = (const float*)d_in[5];
    const float* b1       = (const float*)d_in[6];
    const float* W2       = (const float*)d_in[7];
    const float* g2       = (const float*)d_in[8];
    const float* b2       = (const float*)d_in[9];
    const int*   pool_seg = (const int*)d_in[10];
    const int*   conv_in  = (const int*)d_in[11];
    const int*   conv_out = (const int*)d_in[12];

    int N = in_sizes[0] / CIN;
    int M = out_size / COUT;
    int L = in_sizes[11] / KVOL;

    char* ws = (char*)d_ws;
    size_t off = 0;
    auto alloc = [&](size_t bytes) -> void* {
        void* p = ws + off;
        off = (off + bytes + 255) & ~(size_t)255;
        return p;
    };
    float*          o1      = (float*)alloc((size_t)M * COUT * 4);
    unsigned short* down_bf = (unsigned short*)alloc((size_t)M * COUT * 2);
    unsigned short* o1t     = (unsigned short*)alloc((size_t)M * COUT * 2);
    unsigned short* t_bf    = (unsigned short*)alloc((size_t)N * COUT * 2);
    int*            nbrT    = (int*)alloc((size_t)KVOL * M * 4);
    unsigned short* Wt1     = (unsigned short*)alloc((size_t)KVOL * COUT * COUT * 2);
    unsigned short* Wt2     = (unsigned short*)alloc((size_t)KVOL * COUT * COUT * 2);
    unsigned short* Wdt     = (unsigned short*)alloc((size_t)CIN * COUT * 2);
    int*            bucket  = (int*)alloc((size_t)M * 16 * 4);
    int*            cnt     = (int*)alloc((size_t)M * 4);         // cnt and red are
    float*          red     = (float*)alloc((size_t)768 * 4);     // adjacent: 1 memset
    float* red0 = red, *red1 = red + 512, *red2 = red + 640;

    hipMemsetAsync(nbrT, 0xFF, (size_t)KVOL * M * 4, stream);     // -1 = missing nbr
    hipMemsetAsync(cnt, 0, (size_t)((char*)(red + 768) - (char*)cnt), stream);

    int nbB = (N + 255) / 256, nbL = (L + 255) / 256;
    prep_kernel<<<55 + nbB + nbL * KVOL, 256, 0, stream>>>(
        W1, W2, Wd, Wt1, Wt2, Wdt, pool_seg, cnt, bucket, N,
        conv_out, conv_in, nbrT, L, M, nbB, nbL);
    gemm_t_kernel<<<1024, 256, 0, stream>>>(feats, Wdt, N, t_bf, red0);
    pool_max_kernel<<<(M * 16 + 255) / 256, 256, 0, stream>>>(
        t_bf, cnt, bucket, red0, g0, b0, down_bf, M, N);

    int cblocks = (M + 255) / 256;
    int n4 = (M * COUT) / 4;
    conv_mfma_kernel<<<cblocks, 512, 0, stream>>>(down_bf, Wt1, nbrT, M, o1, red1);
    bn_elu_cvt_kernel<<<(n4 + 255) / 256, 256, 0, stream>>>(o1, red1, g1, b1, o1t, n4, M);
    conv_mfma_kernel<<<cblocks, 512, 0, stream>>>(o1t, Wt2, nbrT, M, (float*)d_out, red2);
    final_kernel<<<(n4 + 255) / 256, 256, 0, stream>>>(
        (float*)d_out, down_bf, red2, g2, b2, n4, M);
}